// Round 7
// baseline (97.190 us; speedup 1.0000x reference)
//
#include <hip/hip_runtime.h>

typedef __bf16 bf16_t;
typedef __bf16 bf16x8 __attribute__((ext_vector_type(8)));
typedef __bf16 bf16x4 __attribute__((ext_vector_type(4)));
typedef float  f32x4  __attribute__((ext_vector_type(4)));
typedef _Float16 f16_t;
typedef _Float16 f16x8 __attribute__((ext_vector_type(8)));
typedef _Float16 f16x4 __attribute__((ext_vector_type(4)));

#define TSEQ 4096
#define SEGS 8

// lgkm-only barrier (proj): in-flight global prefetches survive it.
__device__ __forceinline__ void barrier_lds() {
    __builtin_amdgcn_sched_barrier(0);
    asm volatile("s_waitcnt lgkmcnt(0)" ::: "memory");
    __builtin_amdgcn_s_barrier();
    __builtin_amdgcn_sched_barrier(0);
}

// ---------------------------------------------------------------------------
// wsplit: W[1024][64] (q,k,v fp32) -> wT[192][1024] bf16 (transposed).
// Wq pre-scaled by 0.125*log2(e) so attention scores land in exp2 domain.
// ---------------------------------------------------------------------------
__global__ __launch_bounds__(256) void wsplit_k(
    const float* __restrict__ Wq, const float* __restrict__ Wk,
    const float* __restrict__ Wv, bf16_t* __restrict__ wT)
{
    __shared__ bf16_t th[64][72];
    const int mat = blockIdx.x >> 4;
    const int kb  = (blockIdx.x & 15) * 64;
    const float* W = (mat == 0) ? Wq : ((mat == 1) ? Wk : Wv);
    const float scale = (mat == 0) ? 0.18033688011112042f : 1.0f;
    const int t  = threadIdx.x;
    const int kl = t >> 2;
    const int dc = (t & 3) * 16;
    #pragma unroll
    for (int i = 0; i < 4; ++i) {
        float4 v = *reinterpret_cast<const float4*>(W + (long)(kb + kl) * 64 + dc + 4 * i);
        th[dc + 4*i + 0][kl] = (bf16_t)(v.x * scale);
        th[dc + 4*i + 1][kl] = (bf16_t)(v.y * scale);
        th[dc + 4*i + 2][kl] = (bf16_t)(v.z * scale);
        th[dc + 4*i + 3][kl] = (bf16_t)(v.w * scale);
    }
    __syncthreads();
    const int d  = t >> 2;
    const int kc = (t & 3) * 16;
    bf16x8 a0 = *reinterpret_cast<const bf16x8*>(&th[d][kc]);
    bf16x8 a1 = *reinterpret_cast<const bf16x8*>(&th[d][kc + 8]);
    long o = (long)(mat * 64 + d) * 1024 + kb + kc;
    *reinterpret_cast<bf16x8*>(wT + o)     = a0;
    *reinterpret_cast<bf16x8*>(wT + o + 8) = a1;
}

// ---------------------------------------------------------------------------
// proj: [8192][192] = X @ W^T.  512 blocks = 128 row-groups x 4 N-blocks;
// 4 waves M-split.  X direct-to-frags (2-step ping-pong), W dbuf in LDS.
// In-loop barriers are lgkm-only so X/W prefetches stay in flight.
// ---------------------------------------------------------------------------
__global__ __launch_bounds__(256, 2) void proj_mfma(
    const float* __restrict__ X, const bf16_t* __restrict__ wT,
    bf16_t* __restrict__ qh, bf16_t* __restrict__ kh, bf16_t* __restrict__ vt)
{
    __shared__ __align__(16) unsigned char smem[13824];
    bf16_t (*wl)[48][72] = reinterpret_cast<bf16_t(*)[48][72]>(smem);   // [2][48][72]
    float  (*vtl)[68]    = reinterpret_cast<float(*)[68]>(smem);        // [48][68] (union)

    const int tid = threadIdx.x, lane = tid & 63;
    const int mw  = tid >> 6;
    const int q4 = lane & 15, g = lane >> 4;
    const int bx = blockIdx.x;
    const int rg = bx & 127, nb = bx >> 7;
    const long R0 = (long)rg * 64;

    const float* xrow = X + (R0 + 16 * mw + q4) * 1024 + 8 * g;

    const int wrow = tid >> 2, c16 = (tid & 3) * 16;
    const bf16_t* wsrc = wT + (long)(48 * nb + wrow) * 1024 + c16;
    const bool wact = (tid < 192);

    bf16x8 wr0, wr1;
    float4 xE[4], xO[4];
    f32x4 acc[3] = {};

    auto loadW = [&](int t) {
        if (wact) {
            wr0 = *reinterpret_cast<const bf16x8*>(wsrc + t * 64);
            wr1 = *reinterpret_cast<const bf16x8*>(wsrc + t * 64 + 8);
        }
    };
    auto writeW = [&](int buf) {
        if (wact) {
            *reinterpret_cast<bf16x8*>(&wl[buf][wrow][c16])     = wr0;
            *reinterpret_cast<bf16x8*>(&wl[buf][wrow][c16 + 8]) = wr1;
        }
    };
    auto loadX = [&](int t, float4 (&xc)[4]) {
        xc[0] = *reinterpret_cast<const float4*>(xrow + t * 64);
        xc[1] = *reinterpret_cast<const float4*>(xrow + t * 64 + 4);
        xc[2] = *reinterpret_cast<const float4*>(xrow + t * 64 + 32);
        xc[3] = *reinterpret_cast<const float4*>(xrow + t * 64 + 36);
    };

    loadW(0); writeW(0);
    loadW(1);
    loadX(0, xE); loadX(1, xO);
    asm volatile("" ::: "memory");
    barrier_lds();

    auto stepf = [&](int t, float4 (&xc)[4]) {
        if (t + 1 < 16) {
            writeW((t + 1) & 1);
            loadW(t + 2 < 16 ? t + 2 : 15);
        }
        bf16x8 a0 = {(bf16_t)xc[0].x, (bf16_t)xc[0].y, (bf16_t)xc[0].z, (bf16_t)xc[0].w,
                     (bf16_t)xc[1].x, (bf16_t)xc[1].y, (bf16_t)xc[1].z, (bf16_t)xc[1].w};
        bf16x8 a1 = {(bf16_t)xc[2].x, (bf16_t)xc[2].y, (bf16_t)xc[2].z, (bf16_t)xc[2].w,
                     (bf16_t)xc[3].x, (bf16_t)xc[3].y, (bf16_t)xc[3].z, (bf16_t)xc[3].w};
        if (t + 2 < 16) loadX(t + 2, xc);
        asm volatile("" ::: "memory");
        __builtin_amdgcn_s_setprio(1);
        #pragma unroll
        for (int j = 0; j < 3; ++j) {
            bf16x8 b0 = *reinterpret_cast<const bf16x8*>(&wl[t & 1][16 * j + q4][8 * g]);
            bf16x8 b1 = *reinterpret_cast<const bf16x8*>(&wl[t & 1][16 * j + q4][8 * g + 32]);
            acc[j] = __builtin_amdgcn_mfma_f32_16x16x32_bf16(a0, b0, acc[j], 0, 0, 0);
            acc[j] = __builtin_amdgcn_mfma_f32_16x16x32_bf16(a1, b1, acc[j], 0, 0, 0);
        }
        __builtin_amdgcn_s_setprio(0);
        barrier_lds();
    };
    #pragma unroll
    for (int tt = 0; tt < 16; tt += 2) { stepf(tt, xE); stepf(tt + 1, xO); }

    const int vbase = (nb == 2) ? 0 : 16;
    #pragma unroll
    for (int j = 0; j < 3; ++j) {
        const int nt = 3 * nb + j;
        #pragma unroll
        for (int r = 0; r < 4; ++r) {
            const long row = R0 + 16 * mw + 4 * g + r;
            const float vv = acc[j][r];
            if (nt < 4)      qh[row * 64 + nt * 16 + q4] = (bf16_t)vv;
            else if (nt < 8) kh[row * 64 + (nt - 4) * 16 + q4] = (bf16_t)vv;
            else             vtl[(nt - 8) * 16 + q4 - vbase][16 * mw + 4 * g + r] = vv;
        }
    }
    if (nb >= 2) {
        barrier_lds();
        const int nd = (nb == 2) ? 16 : 48;
        const int dl = tid >> 2, cc = (tid & 3) * 16;
        if (dl < nd) {
            bf16x8 o0, o1;
            #pragma unroll
            for (int i = 0; i < 8; ++i) {
                o0[i] = (bf16_t)vtl[dl][cc + i];
                o1[i] = (bf16_t)vtl[dl][cc + 8 + i];
            }
            bf16_t* dst = vt + (long)(vbase + dl) * 8192 + R0 + cc;
            *reinterpret_cast<bf16x8*>(dst)     = o0;
            *reinterpret_cast<bf16x8*>(dst + 8) = o1;
        }
    }
}

// ---------------------------------------------------------------------------
// attn: flash, 1-WAVE blocks (64 thr, 16 queries), NO barriers, self-paced.
// K refilled into the same regs after its last use (T14 issue-early); V
// issued at iter top, consumed at PV ~600cyc later.  P via 2KB per-wave LDS
// (lgkm-only).  Causal mask peeled to diag chunk; exact defer-rescale (T13).
// ~16 independent waves/CU -> latency self-hiding.  exp2 domain.
// ---------------------------------------------------------------------------
__global__ __launch_bounds__(64, 4) void attn_mfma(
    const bf16_t* __restrict__ qh, const bf16_t* __restrict__ kh,
    const bf16_t* __restrict__ vt,
    f16_t* __restrict__ pO, float* __restrict__ pm, float* __restrict__ pl)
{
    __shared__ __align__(16) unsigned char smem[2304];
    bf16_t (*P)[16][8] = reinterpret_cast<bf16_t(*)[16][8]>(smem);  // [8][16][8]
    f16_t  (*ot)[72]   = reinterpret_cast<f16_t(*)[72]>(smem);      // [16][72] overlay

    const int lane = threadIdx.x;
    const int q4 = lane & 15, g = lane >> 4;
    const int bx = blockIdx.x;
    const int b = bx >> 11;                 // batch-major: XCDs see one batch at a time
    const int inner = bx & 2047;
    const int qi = 255 - (inner >> 3);      // heavy tiles first
    const int seg = inner & 7;
    const int C = (qi >> 2) + 1;            // causal 64-key chunk count
    if (seg >= C) return;
    const long base = (long)b * TSEQ;
    const int r0 = qi << 4;

    const bf16_t* qr = qh + (base + r0 + q4) * 64 + 8 * g;
    const bf16x8 qf0 = *reinterpret_cast<const bf16x8*>(qr);
    const bf16x8 qf1 = *reinterpret_cast<const bf16x8*>(qr + 32);

    bf16x8 kf[4][2], vf[4][2];
    auto loadK = [&](int kb) {
        #pragma unroll
        for (int kt = 0; kt < 4; ++kt) {
            const bf16_t* kr = kh + (base + kb + kt * 16 + q4) * 64 + 8 * g;
            kf[kt][0] = *reinterpret_cast<const bf16x8*>(kr);
            kf[kt][1] = *reinterpret_cast<const bf16x8*>(kr + 32);
        }
    };
    auto loadV = [&](int kb) {
        #pragma unroll
        for (int dt = 0; dt < 4; ++dt) {
            const bf16_t* vr = vt + (long)(dt * 16 + q4) * 8192 + base + kb + 8 * g;
            vf[dt][0] = *reinterpret_cast<const bf16x8*>(vr);
            vf[dt][1] = *reinterpret_cast<const bf16x8*>(vr + 32);
        }
    };

    float m = -1e30f, l = 0.f;
    f32x4 oacc[4] = {};

    loadK(seg << 6);

    for (int c = seg; c < C; c += SEGS) {
        const int kb = c << 6;
        loadV(kb);                               // V(c): consumed at PV below
        asm volatile("" ::: "memory");

        // ---- QK^T (swapped): S^T[key][query]; consumes kf
        f32x4 sacc[4];
        #pragma unroll
        for (int kt = 0; kt < 4; ++kt) {
            f32x4 a = {};
            a = __builtin_amdgcn_mfma_f32_16x16x32_bf16(kf[kt][0], qf0, a, 0, 0, 0);
            a = __builtin_amdgcn_mfma_f32_16x16x32_bf16(kf[kt][1], qf1, a, 0, 0, 0);
            sacc[kt] = a;
        }
        // refill kf for next chunk (after last use -> RA reuses same regs)
        if (c + SEGS < C) {
            loadK((c + SEGS) << 6);
            asm volatile("" ::: "memory");
        }

        // ---- causal mask: only the diagonal chunk (uniform branch)
        if (c == C - 1) {
            #pragma unroll
            for (int kt = 0; kt < 4; ++kt)
                #pragma unroll
                for (int r = 0; r < 4; ++r)
                    if (kb + kt * 16 + 4 * g + r > r0 + q4) sacc[kt][r] = -1e30f;
        }

        // ---- per-query max (16 local + cross-g shfl)
        float mx = sacc[0][0];
        #pragma unroll
        for (int kt = 0; kt < 4; ++kt)
            #pragma unroll
            for (int r = 0; r < 4; ++r) mx = fmaxf(mx, sacc[kt][r]);
        mx = fmaxf(mx, __shfl_xor(mx, 16));
        mx = fmaxf(mx, __shfl_xor(mx, 32));

        // ---- exp2 in place; exact defer-rescale when max didn't grow
        float lsum = 0.f;
        if (__all(mx <= m)) {
            #pragma unroll
            for (int kt = 0; kt < 4; ++kt)
                #pragma unroll
                for (int r = 0; r < 4; ++r) {
                    float e = __builtin_exp2f(sacc[kt][r] - m);
                    sacc[kt][r] = e; lsum += e;
                }
        } else {
            const float mnew = fmaxf(m, mx);
            const float alpha = __builtin_exp2f(m - mnew);
            m = mnew;
            #pragma unroll
            for (int kt = 0; kt < 4; ++kt)
                #pragma unroll
                for (int r = 0; r < 4; ++r) {
                    float e = __builtin_exp2f(sacc[kt][r] - mnew);
                    sacc[kt][r] = e; lsum += e;
                }
            #pragma unroll
            for (int dt = 0; dt < 4; ++dt) oacc[dt] *= alpha;
            l *= alpha;
        }
        lsum += __shfl_xor(lsum, 16);
        lsum += __shfl_xor(lsum, 32);
        l += lsum;

        // ---- pack P -> per-wave LDS tile (no barrier: same wave, lgkm only)
        #pragma unroll
        for (int kt = 0; kt < 4; ++kt) {
            bf16x4 hv = {(bf16_t)sacc[kt][0], (bf16_t)sacc[kt][1],
                         (bf16_t)sacc[kt][2], (bf16_t)sacc[kt][3]};
            *reinterpret_cast<bf16x4*>(&P[2 * kt + (g >> 1)][q4][(g & 1) << 2]) = hv;
        }
        bf16x8 ph0 = *reinterpret_cast<const bf16x8*>(&P[g][q4][0]);
        bf16x8 ph1 = *reinterpret_cast<const bf16x8*>(&P[4 + g][q4][0]);

        // ---- PV: O^T += V^T x P^T (vf issued ~600cyc ago)
        #pragma unroll
        for (int dt = 0; dt < 4; ++dt) {
            oacc[dt] = __builtin_amdgcn_mfma_f32_16x16x32_bf16(vf[dt][0], ph0, oacc[dt], 0, 0, 0);
            oacc[dt] = __builtin_amdgcn_mfma_f32_16x16x32_bf16(vf[dt][1], ph1, oacc[dt], 0, 0, 0);
        }
    }

    // ---- epilogue: normalize, transpose via LDS (overlays P), store f16
    const float invl = 1.0f / l;
    #pragma unroll
    for (int dt = 0; dt < 4; ++dt)
        #pragma unroll
        for (int r = 0; r < 4; ++r)
            ot[q4][dt * 16 + 4 * g + r] = (f16_t)(oacc[dt][r] * invl);

    const long pb = ((long)b * 256 + qi) * SEGS + seg;
    {
        const int q  = lane >> 2;
        const int dc = (lane & 3) << 4;
        f16x8 o0 = *reinterpret_cast<const f16x8*>(&ot[q][dc]);
        f16x8 o1 = *reinterpret_cast<const f16x8*>(&ot[q][dc + 8]);
        f16_t* dst = pO + (pb * 16 + q) * 64 + dc;
        *reinterpret_cast<f16x8*>(dst)     = o0;
        *reinterpret_cast<f16x8*>(dst + 8) = o1;
    }
    if (g == 0) {
        pm[pb * 16 + q4] = m;
        pl[pb * 16 + q4] = l;
    }
}

// ---------------------------------------------------------------------------
// merge: combine active segs per 16q tile -> final O (fp32).  exp2 domain.
// ---------------------------------------------------------------------------
__global__ __launch_bounds__(256) void merge_k(
    const f16_t* __restrict__ pO, const float* __restrict__ pm,
    const float* __restrict__ pl, float* __restrict__ O)
{
    const int tile = blockIdx.x, b = blockIdx.y;   // 256 tiles of 16 queries
    const int C = (tile >> 2) + 1;
    const int S = (C < SEGS) ? C : SEGS;
    const int t = threadIdx.x;
    const int q = t >> 4, dc = (t & 15) << 2;
    const long pb = ((long)b * 256 + tile) * SEGS;

    float mstar = -1e30f;
    for (int s = 0; s < S; ++s) mstar = fmaxf(mstar, pm[(pb + s) * 16 + q]);
    float L = 0.f;
    float o[4] = {0.f, 0.f, 0.f, 0.f};
    for (int s = 0; s < S; ++s) {
        const float ws = __builtin_exp2f(pm[(pb + s) * 16 + q] - mstar) * pl[(pb + s) * 16 + q];
        L += ws;
        const f16_t* src = pO + ((pb + s) * 16 + q) * 64 + dc;
        f16x4 a = *reinterpret_cast<const f16x4*>(src);
        #pragma unroll
        for (int i = 0; i < 4; ++i) o[i] += ws * (float)a[i];
    }
    const float inv = 1.0f / L;
    f32x4 v = {o[0] * inv, o[1] * inv, o[2] * inv, o[3] * inv};
    *reinterpret_cast<f32x4*>(O + ((long)b * TSEQ + tile * 16 + q) * 64 + dc) = v;
}

extern "C" void kernel_launch(void* const* d_in, const int* in_sizes, int n_in,
                              void* d_out, int out_size, void* d_ws, size_t ws_size,
                              hipStream_t stream)
{
    const float* X  = (const float*)d_in[0];
    const float* Wq = (const float*)d_in[1];
    const float* Wk = (const float*)d_in[2];
    const float* Wv = (const float*)d_in[3];
    float* O = (float*)d_out;

    char* ws = (char*)d_ws;
    size_t off = 0;
    bf16_t* wT = (bf16_t*)(ws + off); off += 192 * 1024 * sizeof(bf16_t);
    bf16_t* qh = (bf16_t*)(ws + off); off += 8192L * 64 * sizeof(bf16_t);
    bf16_t* kh = (bf16_t*)(ws + off); off += 8192L * 64 * sizeof(bf16_t);
    bf16_t* vt = (bf16_t*)(ws + off); off += 64L * 8192 * sizeof(bf16_t);
    f16_t*  pO = (f16_t*)(ws + off);  off += 2L * 256 * SEGS * 16 * 64 * sizeof(f16_t);
    float*  pm = (float*)(ws + off);  off += 2L * 256 * SEGS * 16 * sizeof(float);
    float*  pl = (float*)(ws + off);  off += 2L * 256 * SEGS * 16 * sizeof(float);

    wsplit_k <<<48, 256, 0, stream>>>(Wq, Wk, Wv, wT);
    proj_mfma<<<512, 256, 0, stream>>>(X, wT, qh, kh, vt);
    attn_mfma<<<dim3(4096), 64, 0, stream>>>(qh, kh, vt, pO, pm, pl);
    merge_k  <<<dim3(256, 2), 256, 0, stream>>>(pO, pm, pl, O);
}